// Round 1
// baseline (103.684 us; speedup 1.0000x reference)
//
#include <hip/hip_runtime.h>
#include <math.h>

#define BB 32
#define NN 2048

// ws layout (floats):
// [0..B)      sum_p per batch  (Σ sqrt(min d2)*pvf)
// [B..2B)     sum_t per batch
// [2B..3B)    cnt_p per batch
// [3B..4B)    cnt_t per batch
// [4B+0]      sum_point   (Σ (dx²+dy²)·vm)
// [4B+1]      sum_struct  (Σ (dx²+dy²)·total_mask)
// [4B+2]      sum_mask    (Σ total_mask)

__device__ __forceinline__ float wred(float v) {
#pragma unroll
    for (int o = 32; o > 0; o >>= 1) v += __shfl_down(v, o, 64);
    return v;
}

__global__ __launch_bounds__(256) void chamfer_pass(
    const float* __restrict__ pred, const float* __restrict__ tgt,
    const float* __restrict__ smask, float* __restrict__ ws)
{
    __shared__ float2 sR[NN];
    __shared__ float sred[5 * 4];

    const int tid  = threadIdx.x;
    const int b    = blockIdx.y;
    const int role = blockIdx.z;   // 0: query=pred ref=tgt; 1: query=tgt ref=pred

    const float* q = (role == 0) ? pred : tgt;
    const float* r = (role == 0) ? tgt  : pred;
    const float* rb = r + (size_t)b * NN * 3;

    // Stage refs: invisible refs get poisoned coords -> d2 ~ 2e18, never the min.
    for (int m = tid; m < NN; m += 256) {
        float rx = rb[3 * m + 0];
        float ry = rb[3 * m + 1];
        float rv = rb[3 * m + 2];
        if (rv != 1.0f) { rx = 1.0e9f; ry = 1.0e9f; }
        sR[m] = make_float2(rx, ry);
    }
    __syncthreads();

    const int n = blockIdx.x * 256 + tid;
    const float* qp = q + ((size_t)b * NN + n) * 3;
    const float px = qp[0], py = qp[1], qv = qp[2];
    const float qvf = (qv == 1.0f) ? 1.0f : 0.0f;

    float m0 = 3.4e38f, m1 = 3.4e38f, m2 = 3.4e38f, m3 = 3.4e38f;
#pragma unroll 2
    for (int m = 0; m < NN; m += 4) {
        float2 t0 = sR[m + 0];
        float2 t1 = sR[m + 1];
        float2 t2 = sR[m + 2];
        float2 t3 = sR[m + 3];
        float dx0 = px - t0.x, dy0 = py - t0.y;
        float dx1 = px - t1.x, dy1 = py - t1.y;
        float dx2 = px - t2.x, dy2 = py - t2.y;
        float dx3 = px - t3.x, dy3 = py - t3.y;
        m0 = fminf(m0, fmaf(dx0, dx0, dy0 * dy0));
        m1 = fminf(m1, fmaf(dx1, dx1, dy1 * dy1));
        m2 = fminf(m2, fmaf(dx2, dx2, dy2 * dy2));
        m3 = fminf(m3, fmaf(dx3, dx3, dy3 * dy3));
    }
    float mn = fminf(fminf(m0, m1), fminf(m2, m3));
    // min(sqrt(max(d2,EPS))) == sqrt(max(min(d2),EPS)) : clamp+sqrt once.
    float contrib = sqrtf(fmaxf(mn, 1e-12f)) * qvf;

    // Point/structure stats: only in role 0 so each (b,n) counted once.
    float pt = 0.0f, st = 0.0f, mk = 0.0f;
    if (role == 0) {
        const float* tp = tgt + ((size_t)b * NN + n) * 3;
        float tx = tp[0], ty = tp[1], tv = tp[2];
        float vm = (tv == 1.0f) ? 1.0f : 0.0f;
        float dx = px - tx, dy = py - ty;
        float e2 = fmaf(dx, dx, dy * dy);
        float s0 = smask[((size_t)b * NN + n) * 2 + 0];
        float s1 = smask[((size_t)b * NN + n) * 2 + 1];
        float sm = fminf(fmaxf(s0 + s1, 0.0f), 1.0f);
        float tm = sm * vm;
        pt = e2 * vm;   // mask is 0/1 so mask^2 == mask
        st = e2 * tm;
        mk = tm;
    }

    // Block-reduce 5 quantities, then a handful of atomics per block.
    float v[5] = {contrib, qvf, pt, st, mk};
    const int wave = tid >> 6, lane = tid & 63;
#pragma unroll
    for (int i = 0; i < 5; i++) {
        float rv2 = wred(v[i]);
        if (lane == 0) sred[i * 4 + wave] = rv2;
    }
    __syncthreads();
    if (tid == 0) {
#pragma unroll
        for (int i = 0; i < 5; i++)
            v[i] = sred[i * 4 + 0] + sred[i * 4 + 1] + sred[i * 4 + 2] + sred[i * 4 + 3];
        if (role == 0) {
            atomicAdd(&ws[b], v[0]);            // sum_p
            atomicAdd(&ws[2 * BB + b], v[1]);   // cnt_p
            atomicAdd(&ws[4 * BB + 0], v[2]);   // sum_point
            atomicAdd(&ws[4 * BB + 1], v[3]);   // sum_struct
            atomicAdd(&ws[4 * BB + 2], v[4]);   // sum_mask
        } else {
            atomicAdd(&ws[BB + b], v[0]);       // sum_t
            atomicAdd(&ws[3 * BB + b], v[1]);   // cnt_t
        }
    }
}

__global__ __launch_bounds__(64) void finalize_k(
    const float* __restrict__ ws, float* __restrict__ out)
{
    const int lane = threadIdx.x;
    float ch = 0.0f;
    if (lane < BB) {
        float cp = ws[2 * BB + lane];
        float ct = ws[3 * BB + lane];
        float mp = ws[lane] / fmaxf(cp, 1.0f);
        float mt = ws[BB + lane] / fmaxf(ct, 1.0f);
        ch = (cp > 0.0f && ct > 0.0f) ? 0.5f * (mp + mt) : 0.0f;
    }
    ch = wred(ch);
    if (lane == 0) {
        float loss_chamfer = ch / (float)BB;
        const float denom = (float)BB * (float)NN * 2.0f;
        float loss_point = ws[4 * BB + 0] / denom;
        float sum_mask = ws[4 * BB + 2];
        float loss_struct = (sum_mask > 0.0f) ? ws[4 * BB + 1] / denom : 0.0f;
        float total = 1.0f * loss_point + 5.0f * loss_chamfer + 2.0f * loss_struct;
        out[0] = total;
        out[1] = loss_point;
        out[2] = 0.0f;
        out[3] = loss_chamfer;
    }
}

extern "C" void kernel_launch(void* const* d_in, const int* in_sizes, int n_in,
                              void* d_out, int out_size, void* d_ws, size_t ws_size,
                              hipStream_t stream)
{
    const float* pred  = (const float*)d_in[0];
    const float* tgt   = (const float*)d_in[1];
    const float* smask = (const float*)d_in[2];
    float* out = (float*)d_out;
    float* ws  = (float*)d_ws;

    // ws is re-poisoned 0xAA before every timed call -> zero the accumulators.
    hipMemsetAsync(d_ws, 0, (4 * BB + 3) * sizeof(float), stream);

    dim3 grid(NN / 256, BB, 2);
    chamfer_pass<<<grid, 256, 0, stream>>>(pred, tgt, smask, ws);
    finalize_k<<<1, 64, 0, stream>>>(ws, out);
}

// Round 2
// 82.764 us; speedup vs baseline: 1.2528x; 1.2528x over previous
//
#include <hip/hip_runtime.h>
#include <math.h>

#define BB 32
#define NN 2048
#define TB 256            // threads per block (K1, K2)
#define QT 4              // queries per thread in K1
#define QPB (QT * TB)     // 1024 queries per K1 block
#define QB (NN / QPB)     // 2 query-blocks per (b, role)
#define K2_QB (NN / TB)   // 8 query-blocks per (b, role) in K2

// ws layout (floats):
//   part[0 .. 2*BB*NN*R)            partial mins+|q|^2, idx ((role*BB+b)*NN+q)*R + rc
//   bsum[5][512] after that         per-K2-block partial sums:
//     arr 0: contrib (sqrt(min d2)*vis)   arr 1: vis count
//     arr 2: point err sum                arr 3: struct err sum   arr 4: mask sum

__device__ __forceinline__ float wred(float v) {
#pragma unroll
    for (int o = 32; o > 0; o >>= 1) v += __shfl_down(v, o, 64);
    return v;
}

// K1: for each query, partial min over one ref-chunk of (|r|^2 - 2 q.r), plus |q|^2.
// grid: (QB, BB, 2*R); blockIdx.z = rc*2 + role
__global__ __launch_bounds__(256) void k1_chamfer(
    const float* __restrict__ pred, const float* __restrict__ tgt,
    float* __restrict__ part, int R)
{
    __shared__ float4 sref[NN];   // 32 KB: supports up to a full-ref chunk

    const int tid  = threadIdx.x;
    const int b    = blockIdx.y;
    const int role = blockIdx.z & 1;
    const int rc   = blockIdx.z >> 1;
    const int M    = NN / R;      // refs in this chunk

    const float* q = role ? tgt : pred;
    const float* r = role ? pred : tgt;
    const float* rb = r + ((size_t)b * NN + (size_t)rc * M) * 3;

    // Stage refs in norm form; invisible refs poisoned far away (d2 ~ 2e18).
    for (int m = tid; m < M; m += TB) {
        float rx = rb[3 * m + 0];
        float ry = rb[3 * m + 1];
        float rv = rb[3 * m + 2];
        if (rv != 1.0f) { rx = 1.0e9f; ry = 1.0e9f; }
        sref[m] = make_float4(-2.0f * rx, -2.0f * ry, fmaf(rx, rx, ry * ry), 0.0f);
    }
    __syncthreads();

    const float* qb_ = q + (size_t)b * NN * 3;
    const int q0 = blockIdx.x * QPB + tid;

    float px[QT], py[QT], mn[QT];
#pragma unroll
    for (int j = 0; j < QT; j++) {
        int qi = q0 + j * TB;
        px[j] = qb_[3 * qi + 0];
        py[j] = qb_[3 * qi + 1];
        mn[j] = 3.4e38f;
    }

#pragma unroll 4
    for (int m = 0; m < M; m++) {
        float4 t = sref[m];   // wave-uniform -> broadcast, conflict-free
#pragma unroll
        for (int j = 0; j < QT; j++) {
            float s = fmaf(px[j], t.x, fmaf(py[j], t.y, t.z));
            mn[j] = fminf(mn[j], s);
        }
    }

#pragma unroll
    for (int j = 0; j < QT; j++) {
        int qi = q0 + j * TB;
        float qn = fmaf(px[j], px[j], py[j] * py[j]);
        part[((size_t)(role * BB + b) * NN + qi) * (size_t)R + rc] = qn + mn[j];
    }
}

// K2: combine R partials per query, sqrt+mask, block-reduce 5 sums, plain store.
// grid: (K2_QB, BB, 2)
__global__ __launch_bounds__(256) void k2_combine(
    const float* __restrict__ pred, const float* __restrict__ tgt,
    const float* __restrict__ smask, const float* __restrict__ part,
    float* __restrict__ bsum, int R)
{
    __shared__ float sred[5 * 4];
    const int tid  = threadIdx.x;
    const int b    = blockIdx.y;
    const int role = blockIdx.z;
    const int qi   = blockIdx.x * TB + tid;

    const float* pbase = part + ((size_t)(role * BB + b) * NN + qi) * (size_t)R;
    float m = 3.4e38f;
    for (int rr = 0; rr < R; rr++) m = fminf(m, pbase[rr]);

    const float* qp = (role ? tgt : pred) + ((size_t)b * NN + qi) * 3;
    float qvf = (qp[2] == 1.0f) ? 1.0f : 0.0f;
    float contrib = sqrtf(fmaxf(m, 1e-12f)) * qvf;

    float pt = 0.0f, st = 0.0f, mk = 0.0f;
    if (role == 0) {
        float px = qp[0], py = qp[1];
        const float* tp = tgt + ((size_t)b * NN + qi) * 3;
        float vm = (tp[2] == 1.0f) ? 1.0f : 0.0f;
        float dx = px - tp[0], dy = py - tp[1];
        float e2 = fmaf(dx, dx, dy * dy);
        float s0 = smask[((size_t)b * NN + qi) * 2 + 0];
        float s1 = smask[((size_t)b * NN + qi) * 2 + 1];
        float tm = fminf(fmaxf(s0 + s1, 0.0f), 1.0f) * vm;
        pt = e2 * vm;
        st = e2 * tm;
        mk = tm;
    }

    float v[5] = {contrib, qvf, pt, st, mk};
    const int wave = tid >> 6, lane = tid & 63;
#pragma unroll
    for (int i = 0; i < 5; i++) {
        float rv = wred(v[i]);
        if (lane == 0) sred[i * 4 + wave] = rv;
    }
    __syncthreads();
    if (tid < 5) {
        int i = tid;
        float s = sred[i * 4 + 0] + sred[i * 4 + 1] + sred[i * 4 + 2] + sred[i * 4 + 3];
        int slot = (role * BB + b) * K2_QB + blockIdx.x;   // 0..511
        bsum[i * (2 * BB * K2_QB) + slot] = s;
    }
}

// K3: assemble the 4 outputs from 5 x 512 block sums. 1 block, 64 threads.
__global__ __launch_bounds__(64) void k3_final(
    const float* __restrict__ bsum, float* __restrict__ out)
{
    const int lane = threadIdx.x;
    const int S = 2 * BB * K2_QB;   // 512

    // chamfer per batch on lanes 0..31
    float ch = 0.0f;
    if (lane < BB) {
        float sp = 0, cp = 0, stt = 0, ct = 0;
#pragma unroll
        for (int x = 0; x < K2_QB; x++) {
            sp += bsum[0 * S + (0 * BB + lane) * K2_QB + x];
            cp += bsum[1 * S + (0 * BB + lane) * K2_QB + x];
            stt += bsum[0 * S + (1 * BB + lane) * K2_QB + x];
            ct += bsum[1 * S + (1 * BB + lane) * K2_QB + x];
        }
        float mp = sp / fmaxf(cp, 1.0f);
        float mt = stt / fmaxf(ct, 1.0f);
        ch = (cp > 0.0f && ct > 0.0f) ? 0.5f * (mp + mt) : 0.0f;
    }
    ch = wred(ch);

    float spt = 0, sst = 0, smk = 0;
    for (int i = lane; i < S; i += 64) {
        spt += bsum[2 * S + i];
        sst += bsum[3 * S + i];
        smk += bsum[4 * S + i];
    }
    spt = wred(spt); sst = wred(sst); smk = wred(smk);

    if (lane == 0) {
        float loss_chamfer = ch / (float)BB;
        const float denom = (float)BB * (float)NN * 2.0f;
        float loss_point = spt / denom;
        float loss_struct = (smk > 0.0f) ? sst / denom : 0.0f;
        out[0] = loss_point + 5.0f * loss_chamfer + 2.0f * loss_struct;
        out[1] = loss_point;
        out[2] = 0.0f;
        out[3] = loss_chamfer;
    }
}

extern "C" void kernel_launch(void* const* d_in, const int* in_sizes, int n_in,
                              void* d_out, int out_size, void* d_ws, size_t ws_size,
                              hipStream_t stream)
{
    const float* pred  = (const float*)d_in[0];
    const float* tgt   = (const float*)d_in[1];
    const float* smask = (const float*)d_in[2];
    float* out = (float*)d_out;
    float* ws  = (float*)d_ws;

    // Pick the largest ref-split fitting ws (plain stores; no init needed).
    int R = 8;
    while (R > 1) {
        size_t need = ((size_t)2 * BB * NN * R + 5 * 2 * BB * K2_QB) * sizeof(float);
        if (need <= ws_size) break;
        R >>= 1;
    }
    float* part = ws;
    float* bsum = ws + (size_t)2 * BB * NN * R;

    k1_chamfer<<<dim3(QB, BB, 2 * R), TB, 0, stream>>>(pred, tgt, part, R);
    k2_combine<<<dim3(K2_QB, BB, 2), TB, 0, stream>>>(pred, tgt, smask, part, bsum, R);
    k3_final<<<1, 64, 0, stream>>>(bsum, out);
}

// Round 3
// 81.255 us; speedup vs baseline: 1.2760x; 1.0186x over previous
//
#include <hip/hip_runtime.h>
#include <math.h>

#define BB 32
#define NN 2048
#define TB 256            // threads per block (K1, K2)
#define QT 8              // queries per thread in K1 -> 2048 = NN per block
#define RCH 8             // ref chunks (split of the min over refs)
#define MCH (NN / RCH)    // 256 refs per chunk
#define K2_QB (NN / TB)   // 8 query-blocks per (b, role) in K2

// ws layout (floats):
//   part[RCH][2*BB][NN]   partial (|q|^2 + min over chunk of (|r|^2-2q.r))
//   bsum[5][512]          per-K2-block partial sums (contrib, vis, pt, st, mk)

__device__ __forceinline__ float wred(float v) {
#pragma unroll
    for (int o = 32; o > 0; o >>= 1) v += __shfl_down(v, o, 64);
    return v;
}

// K1: grid (1, BB, 2*RCH); blockIdx.z = rc*2 + role.
// SoA LDS refs in norm form; 8 queries/thread; min3-fused inner loop.
__global__ __launch_bounds__(256) void k1_chamfer(
    const float* __restrict__ pred, const float* __restrict__ tgt,
    float* __restrict__ part)
{
    __shared__ float sa[MCH], sb[MCH], sc[MCH];

    const int tid  = threadIdx.x;
    const int b    = blockIdx.y;
    const int role = blockIdx.z & 1;
    const int rc   = blockIdx.z >> 1;

    const float* q = role ? tgt : pred;
    const float* r = role ? pred : tgt;
    const float* rb = r + ((size_t)b * NN + (size_t)rc * MCH) * 3;

    // Stage one ref per thread (MCH == TB). Invisible refs poisoned far away.
    {
        float rx = rb[3 * tid + 0];
        float ry = rb[3 * tid + 1];
        float rv = rb[3 * tid + 2];
        if (rv != 1.0f) { rx = 1.0e9f; ry = 1.0e9f; }
        sa[tid] = -2.0f * rx;
        sb[tid] = -2.0f * ry;
        sc[tid] = fmaf(rx, rx, ry * ry);
    }
    __syncthreads();

    const float* qb_ = q + (size_t)b * NN * 3;
    float px[QT], py[QT], mn[QT];
#pragma unroll
    for (int j = 0; j < QT; j++) {
        int qi = tid + j * TB;
        px[j] = qb_[3 * qi + 0];
        py[j] = qb_[3 * qi + 1];
        mn[j] = 3.4e38f;
    }

    // 4 refs per iteration: 3 uniform ds_read_b128 (broadcast), then per query
    // 8 fma + 2 min3 -> 2.5 VALU/pair.
#pragma unroll 2
    for (int m = 0; m < MCH; m += 4) {
        float4 a4 = *(const float4*)&sa[m];
        float4 b4 = *(const float4*)&sb[m];
        float4 c4 = *(const float4*)&sc[m];
#pragma unroll
        for (int j = 0; j < QT; j++) {
            float s0 = fmaf(px[j], a4.x, fmaf(py[j], b4.x, c4.x));
            float s1 = fmaf(px[j], a4.y, fmaf(py[j], b4.y, c4.y));
            float s2 = fmaf(px[j], a4.z, fmaf(py[j], b4.z, c4.z));
            float s3 = fmaf(px[j], a4.w, fmaf(py[j], b4.w, c4.w));
            // ((((s0^s1)^s2)^s3)^mn) folds to two v_min3_f32
            mn[j] = fminf(fminf(fminf(fminf(s0, s1), s2), s3), mn[j]);
        }
    }

#pragma unroll
    for (int j = 0; j < QT; j++) {
        int qi = tid + j * TB;
        float qn = fmaf(px[j], px[j], py[j] * py[j]);
        part[((size_t)rc * (2 * BB) + role * BB + b) * NN + qi] = qn + mn[j];
    }
}

// K2: combine RCH partials per query (coalesced plane reads), sqrt+mask,
// block-reduce 5 sums, plain store. grid: (K2_QB, BB, 2)
__global__ __launch_bounds__(256) void k2_combine(
    const float* __restrict__ pred, const float* __restrict__ tgt,
    const float* __restrict__ smask, const float* __restrict__ part,
    float* __restrict__ bsum)
{
    __shared__ float sred[5 * 4];
    const int tid  = threadIdx.x;
    const int b    = blockIdx.y;
    const int role = blockIdx.z;
    const int qi   = blockIdx.x * TB + tid;

    float m = 3.4e38f;
#pragma unroll
    for (int rc = 0; rc < RCH; rc++)
        m = fminf(m, part[((size_t)rc * (2 * BB) + role * BB + b) * NN + qi]);

    const float* qp = (role ? tgt : pred) + ((size_t)b * NN + qi) * 3;
    float qvf = (qp[2] == 1.0f) ? 1.0f : 0.0f;
    float contrib = sqrtf(fmaxf(m, 1e-12f)) * qvf;

    float pt = 0.0f, st = 0.0f, mk = 0.0f;
    if (role == 0) {
        float px = qp[0], py = qp[1];
        const float* tp = tgt + ((size_t)b * NN + qi) * 3;
        float vm = (tp[2] == 1.0f) ? 1.0f : 0.0f;
        float dx = px - tp[0], dy = py - tp[1];
        float e2 = fmaf(dx, dx, dy * dy);
        float s0 = smask[((size_t)b * NN + qi) * 2 + 0];
        float s1 = smask[((size_t)b * NN + qi) * 2 + 1];
        float tm = fminf(fmaxf(s0 + s1, 0.0f), 1.0f) * vm;
        pt = e2 * vm;
        st = e2 * tm;
        mk = tm;
    }

    float v[5] = {contrib, qvf, pt, st, mk};
    const int wave = tid >> 6, lane = tid & 63;
#pragma unroll
    for (int i = 0; i < 5; i++) {
        float rv = wred(v[i]);
        if (lane == 0) sred[i * 4 + wave] = rv;
    }
    __syncthreads();
    if (tid < 5) {
        int i = tid;
        float s = sred[i * 4 + 0] + sred[i * 4 + 1] + sred[i * 4 + 2] + sred[i * 4 + 3];
        int slot = (role * BB + b) * K2_QB + blockIdx.x;   // 0..511
        bsum[i * (2 * BB * K2_QB) + slot] = s;
    }
}

// K3: assemble 4 outputs from 5 x 512 block sums. 1 block, 64 threads.
__global__ __launch_bounds__(64) void k3_final(
    const float* __restrict__ bsum, float* __restrict__ out)
{
    const int lane = threadIdx.x;
    const int S = 2 * BB * K2_QB;   // 512

    float ch = 0.0f;
    if (lane < BB) {
        float sp = 0, cp = 0, stt = 0, ct = 0;
#pragma unroll
        for (int x = 0; x < K2_QB; x++) {
            sp  += bsum[0 * S + (0 * BB + lane) * K2_QB + x];
            cp  += bsum[1 * S + (0 * BB + lane) * K2_QB + x];
            stt += bsum[0 * S + (1 * BB + lane) * K2_QB + x];
            ct  += bsum[1 * S + (1 * BB + lane) * K2_QB + x];
        }
        float mp = sp / fmaxf(cp, 1.0f);
        float mt = stt / fmaxf(ct, 1.0f);
        ch = (cp > 0.0f && ct > 0.0f) ? 0.5f * (mp + mt) : 0.0f;
    }
    ch = wred(ch);

    float spt = 0, sst = 0, smk = 0;
    for (int i = lane; i < S; i += 64) {
        spt += bsum[2 * S + i];
        sst += bsum[3 * S + i];
        smk += bsum[4 * S + i];
    }
    spt = wred(spt); sst = wred(sst); smk = wred(smk);

    if (lane == 0) {
        float loss_chamfer = ch / (float)BB;
        const float denom = (float)BB * (float)NN * 2.0f;
        float loss_point = spt / denom;
        float loss_struct = (smk > 0.0f) ? sst / denom : 0.0f;
        out[0] = loss_point + 5.0f * loss_chamfer + 2.0f * loss_struct;
        out[1] = loss_point;
        out[2] = 0.0f;
        out[3] = loss_chamfer;
    }
}

extern "C" void kernel_launch(void* const* d_in, const int* in_sizes, int n_in,
                              void* d_out, int out_size, void* d_ws, size_t ws_size,
                              hipStream_t stream)
{
    const float* pred  = (const float*)d_in[0];
    const float* tgt   = (const float*)d_in[1];
    const float* smask = (const float*)d_in[2];
    float* out = (float*)d_out;
    float* ws  = (float*)d_ws;

    float* part = ws;                                        // 4 MB
    float* bsum = ws + (size_t)RCH * 2 * BB * NN;            // + 10 KB

    k1_chamfer<<<dim3(1, BB, 2 * RCH), TB, 0, stream>>>(pred, tgt, part);
    k2_combine<<<dim3(K2_QB, BB, 2), TB, 0, stream>>>(pred, tgt, smask, part, bsum);
    k3_final<<<1, 64, 0, stream>>>(bsum, out);
}